// Round 4
// baseline (440.958 us; speedup 1.0000x reference)
//
#include <hip/hip_runtime.h>

// ShallowRBF: x(8192x2048), centers(4096x2048), beta(4096), W(1000x4096), b(1000)
// out = (exp(-beta*||x-c||) @ W^T) / rowsum + b
//
// R4: gemm2 rebuilt in gemm1's shape: 256x128 block, 128x64 wave-tile
// (MFMA-bound 6 ds_read : 8 MFMA inner loop), BK=64, split-K=2 over C=4096,
// fp32 atomicAdd epilogue into memset-zeroed out. gemm1 untouched (at the
// m97-structure plateau, 886 TF). SQ_LDS_BANK_CONFLICT 1.26e7 shown benign
// (swizzle-invariant, time-invariant) — not chased further.

#define BB 8192
#define DD 2048
#define CC 4096
#define KK 1000
#define KP 1024

typedef unsigned short u16;
typedef __bf16 bf16x8 __attribute__((ext_vector_type(8)));
typedef float f32x16 __attribute__((ext_vector_type(16)));

typedef const void __attribute__((address_space(1)))* gvp_t;
typedef void __attribute__((address_space(3)))* lvp_t;

__device__ __forceinline__ u16 f2bf(float f) {
  union { float f; unsigned u; } v; v.f = f;
  return (u16)((v.u + 0x7fffu + ((v.u >> 16) & 1u)) >> 16);  // RNE
}

// ---- prep: row norms (fp32) + bf16 casts of x and centers ----
__global__ void prep_norm_cast(const float* __restrict__ x, const float* __restrict__ cen,
                               u16* __restrict__ xb, u16* __restrict__ cb,
                               float* __restrict__ x2, float* __restrict__ c2) {
  int row = blockIdx.x;
  const float* src;
  u16* dst;
  float* nrm;
  if (row < BB) {
    src = x + (size_t)row * DD; dst = xb + (size_t)row * DD; nrm = x2 + row;
  } else {
    int r = row - BB;
    src = cen + (size_t)r * DD; dst = cb + (size_t)r * DD; nrm = c2 + r;
  }
  int t = threadIdx.x;
  float s = 0.f;
#pragma unroll
  for (int m = 0; m < 2; ++m) {
    int idx = t + 256 * m;
    float4 v = reinterpret_cast<const float4*>(src)[idx];
    s += v.x * v.x + v.y * v.y + v.z * v.z + v.w * v.w;
    reinterpret_cast<ushort4*>(dst)[idx] =
        make_ushort4(f2bf(v.x), f2bf(v.y), f2bf(v.z), f2bf(v.w));
  }
#pragma unroll
  for (int off = 1; off < 64; off <<= 1) s += __shfl_xor(s, off);
  __shared__ float red[4];
  if ((t & 63) == 0) red[t >> 6] = s;
  __syncthreads();
  if (t == 0) *nrm = red[0] + red[1] + red[2] + red[3];
}

// ---- prep: W cast to bf16, padded to 1024 rows (zeros) ----
__global__ void prep_wcast(const float* __restrict__ W, u16* __restrict__ wb) {
  int row = blockIdx.x;  // 0..1023
  int t = threadIdx.x;
  ushort4* dst = reinterpret_cast<ushort4*>(wb + (size_t)row * CC);
  if (row < KK) {
    const float4* src = reinterpret_cast<const float4*>(W + (size_t)row * CC);
#pragma unroll
    for (int m = 0; m < 4; ++m) {
      float4 v = src[t + 256 * m];
      dst[t + 256 * m] = make_ushort4(f2bf(v.x), f2bf(v.y), f2bf(v.z), f2bf(v.w));
    }
  } else {
#pragma unroll
    for (int m = 0; m < 4; ++m) dst[t + 256 * m] = make_ushort4(0, 0, 0, 0);
  }
}

// ---- GEMM1: 256x128 tile; epilogue e = exp(-beta*dist) -> Ebf ----
__global__ __launch_bounds__(256, 3)
void gemm1_rbf(const u16* __restrict__ Abf, const u16* __restrict__ Bbf,
               const float* __restrict__ x2, const float* __restrict__ c2,
               const float* __restrict__ beta, u16* __restrict__ Ebf) {
  constexpr int Kd = DD;
  __shared__ __align__(16) char smem[49152];  // A: 256x64 bf16 (32KB) + B: 128x64 (16KB)

  const int t = threadIdx.x;
  const int lane = t & 63;
  const int wave = t >> 6;
  const int wr = wave >> 1, wc = wave & 1;  // wave-tile: rows wr*128.., cols wc*64..
  const int l31 = lane & 31, khalf = lane >> 5;

  const int rowBase = blockIdx.y * 256;
  const int colBase = blockIdx.x * 128;

  f32x16 acc[4][2];
#pragma unroll
  for (int i = 0; i < 4; ++i)
#pragma unroll
    for (int j = 0; j < 2; ++j) acc[i][j] = 0.f;

  const int sr = t >> 3;
  const int fstage = ((t >> 3) & 7) ^ (((t >> 6) & 3) << 1);
  const int srcChunkOff = ((t & 7) ^ fstage) * 8;  // elements
  const u16* gA0 = Abf + (size_t)(rowBase + sr) * Kd + srcChunkOff;
  const u16* gB0 = Bbf + (size_t)(colBase + sr) * Kd + srcChunkOff;

  const int fv = (l31 & 7) ^ (((l31 >> 3) & 3) << 1);

  for (int kc = 0; kc < Kd; kc += 64) {
#pragma unroll
    for (int it = 0; it < 8; ++it) {
      const u16* ga = gA0 + (size_t)(32 * it) * Kd + kc;
      __builtin_amdgcn_global_load_lds((gvp_t)ga, (lvp_t)(smem + it * 4096 + t * 16), 16, 0, 0);
    }
#pragma unroll
    for (int it = 0; it < 4; ++it) {
      const u16* gb = gB0 + (size_t)(32 * it) * Kd + kc;
      __builtin_amdgcn_global_load_lds((gvp_t)gb, (lvp_t)(smem + 32768 + it * 4096 + t * 16), 16, 0, 0);
    }
    __syncthreads();
#pragma unroll
    for (int ks = 0; ks < 4; ++ks) {
      const int slot = ((ks * 2 + khalf) ^ fv) * 16;
      bf16x8 af[4], bfr[2];
#pragma unroll
      for (int i = 0; i < 4; ++i) {
        int r = wr * 128 + i * 32 + l31;
        af[i] = *(const bf16x8*)(smem + r * 128 + slot);
      }
#pragma unroll
      for (int j = 0; j < 2; ++j) {
        int r = wc * 64 + j * 32 + l31;
        bfr[j] = *(const bf16x8*)(smem + 32768 + r * 128 + slot);
      }
#pragma unroll
      for (int j = 0; j < 2; ++j)
#pragma unroll
        for (int i = 0; i < 4; ++i)
          acc[i][j] = __builtin_amdgcn_mfma_f32_32x32x16_bf16(af[i], bfr[j], acc[i][j], 0, 0, 0);
    }
    __syncthreads();
  }

  // epilogue: C/D layout col=lane&31, row=(reg&3)+8*(reg>>2)+4*(lane>>5)
  const int rbase = rowBase + wr * 128 + 4 * khalf;
  const int cbase = colBase + wc * 64;
  float c2v[2], bet[2];
  int gcol[2];
#pragma unroll
  for (int j = 0; j < 2; ++j) {
    gcol[j] = cbase + j * 32 + l31;
    c2v[j] = c2[gcol[j]];
    bet[j] = beta[gcol[j]];
  }
#pragma unroll
  for (int i = 0; i < 4; ++i) {
#pragma unroll
    for (int reg = 0; reg < 16; ++reg) {
      int grow = rbase + i * 32 + (reg & 3) + 8 * (reg >> 2);
      float x2v = x2[grow];
#pragma unroll
      for (int j = 0; j < 2; ++j) {
        float d = acc[i][j][reg];
        float sq = fmaxf(x2v + c2v[j] - 2.0f * d, 0.0f);
        float e = __expf(-bet[j] * __builtin_amdgcn_sqrtf(sq));
        Ebf[(size_t)grow * CC + gcol[j]] = f2bf(e);
      }
    }
  }
}

// ---- rowsum: one wave per row of Ebf ----
__global__ void rowsum_k(const u16* __restrict__ Ebf, float* __restrict__ rowsum) {
  const int lane = threadIdx.x & 63;
  const int row = blockIdx.x * 4 + (threadIdx.x >> 6);
  const uint4* p = reinterpret_cast<const uint4*>(Ebf + (size_t)row * CC);
  float s = 0.f;
#pragma unroll
  for (int it = 0; it < 8; ++it) {
    uint4 v = p[lane + 64 * it];
    unsigned w[4] = {v.x, v.y, v.z, v.w};
#pragma unroll
    for (int q = 0; q < 4; ++q) {
      union { unsigned u; float f; } lo, hi;
      lo.u = w[q] << 16;
      hi.u = w[q] & 0xffff0000u;
      s += lo.f + hi.f;
    }
  }
#pragma unroll
  for (int off = 1; off < 64; off <<= 1) s += __shfl_xor(s, off);
  if (lane == 0) rowsum[row] = s;
}

// ---- GEMM2: out += (E @ W^T)/rowsum (+ bias); 256x128 block, split-K=2 ----
__global__ __launch_bounds__(256, 3)
void gemm2_out(const u16* __restrict__ Ebf, const u16* __restrict__ Wbf,
               const float* __restrict__ rowsum, const float* __restrict__ bias,
               float* __restrict__ out) {
  constexpr int Kd = CC;
  __shared__ __align__(16) char smem[49152];  // A: 256x64 (32KB) + B: 128x64 (16KB)

  const int t = threadIdx.x;
  const int lane = t & 63;
  const int wave = t >> 6;
  const int wr = wave >> 1, wc = wave & 1;
  const int l31 = lane & 31, khalf = lane >> 5;

  const int rowBase = blockIdx.y * 256;
  const int colBase = blockIdx.x * 128;
  const int kBase = blockIdx.z * (CC / 2);

  f32x16 acc[4][2];
#pragma unroll
  for (int i = 0; i < 4; ++i)
#pragma unroll
    for (int j = 0; j < 2; ++j) acc[i][j] = 0.f;

  const int sr = t >> 3;
  const int fstage = ((t >> 3) & 7) ^ (((t >> 6) & 3) << 1);
  const int srcChunkOff = ((t & 7) ^ fstage) * 8;
  const u16* gA0 = Ebf + (size_t)(rowBase + sr) * Kd + kBase + srcChunkOff;
  const u16* gB0 = Wbf + (size_t)(colBase + sr) * Kd + kBase + srcChunkOff;
  const int fv = (l31 & 7) ^ (((l31 >> 3) & 3) << 1);

  for (int kc = 0; kc < CC / 2; kc += 64) {
#pragma unroll
    for (int it = 0; it < 8; ++it) {
      const u16* ga = gA0 + (size_t)(32 * it) * Kd + kc;
      __builtin_amdgcn_global_load_lds((gvp_t)ga, (lvp_t)(smem + it * 4096 + t * 16), 16, 0, 0);
    }
#pragma unroll
    for (int it = 0; it < 4; ++it) {
      const u16* gb = gB0 + (size_t)(32 * it) * Kd + kc;
      __builtin_amdgcn_global_load_lds((gvp_t)gb, (lvp_t)(smem + 32768 + it * 4096 + t * 16), 16, 0, 0);
    }
    __syncthreads();
#pragma unroll
    for (int ks = 0; ks < 4; ++ks) {
      const int slot = ((ks * 2 + khalf) ^ fv) * 16;
      bf16x8 af[4], bfr[2];
#pragma unroll
      for (int i = 0; i < 4; ++i) {
        int r = wr * 128 + i * 32 + l31;
        af[i] = *(const bf16x8*)(smem + r * 128 + slot);
      }
#pragma unroll
      for (int j = 0; j < 2; ++j) {
        int r = wc * 64 + j * 32 + l31;
        bfr[j] = *(const bf16x8*)(smem + 32768 + r * 128 + slot);
      }
#pragma unroll
      for (int j = 0; j < 2; ++j)
#pragma unroll
        for (int i = 0; i < 4; ++i)
          acc[i][j] = __builtin_amdgcn_mfma_f32_32x32x16_bf16(af[i], bfr[j], acc[i][j], 0, 0, 0);
    }
    __syncthreads();
  }

  const int rbase = rowBase + wr * 128 + 4 * khalf;
  const int cbase = colBase + wc * 64;
  const bool addBias = (blockIdx.z == 0);
  int gcol[2];
  float bv[2];
#pragma unroll
  for (int j = 0; j < 2; ++j) {
    gcol[j] = cbase + j * 32 + l31;
    bv[j] = (addBias && gcol[j] < KK) ? bias[gcol[j]] : 0.f;
  }
#pragma unroll
  for (int i = 0; i < 4; ++i) {
#pragma unroll
    for (int reg = 0; reg < 16; ++reg) {
      int grow = rbase + i * 32 + (reg & 3) + 8 * (reg >> 2);
      float inv = 1.0f / rowsum[grow];
#pragma unroll
      for (int j = 0; j < 2; ++j) {
        if (gcol[j] < KK)
          atomicAdd(&out[(size_t)grow * KK + gcol[j]], acc[i][j][reg] * inv + bv[j]);
      }
    }
  }
}

// ---- workspace layout (bytes) ----
#define OFF_XB 0u                    // 8192*2048*2 = 33554432
#define OFF_CB 33554432u             // 4096*2048*2 = 16777216
#define OFF_WB 50331648u             // 1024*4096*2 = 8388608
#define OFF_EB 58720256u             // 8192*4096*2 = 67108864
#define OFF_X2 125829120u            // 8192*4
#define OFF_C2 125861888u            // 4096*4
#define OFF_RS 125878272u            // 8192*4

extern "C" void kernel_launch(void* const* d_in, const int* in_sizes, int n_in,
                              void* d_out, int out_size, void* d_ws, size_t ws_size,
                              hipStream_t stream) {
  const float* x = (const float*)d_in[0];
  const float* cen = (const float*)d_in[1];
  const float* beta = (const float*)d_in[2];
  const float* W = (const float*)d_in[3];
  const float* bias = (const float*)d_in[4];
  float* out = (float*)d_out;
  char* ws = (char*)d_ws;

  u16* xb = (u16*)(ws + OFF_XB);
  u16* cb = (u16*)(ws + OFF_CB);
  u16* wb = (u16*)(ws + OFF_WB);
  u16* eb = (u16*)(ws + OFF_EB);
  float* x2 = (float*)(ws + OFF_X2);
  float* c2 = (float*)(ws + OFF_C2);
  float* rowsum = (float*)(ws + OFF_RS);

  hipMemsetAsync(out, 0, (size_t)BB * KK * sizeof(float), stream);
  prep_norm_cast<<<BB + CC, 256, 0, stream>>>(x, cen, xb, cb, x2, c2);
  prep_wcast<<<KP, 256, 0, stream>>>(W, wb);
  gemm1_rbf<<<dim3(CC / 128, BB / 256), 256, 0, stream>>>(xb, cb, x2, c2, beta, eb);
  rowsum_k<<<BB / 4, 256, 0, stream>>>(eb, rowsum);
  gemm2_out<<<dim3(KP / 128, BB / 256, 2), 256, 0, stream>>>(eb, wb, rowsum, bias, out);
}

// Round 5
// 414.658 us; speedup vs baseline: 1.0634x; 1.0634x over previous
//
#include <hip/hip_runtime.h>

// ShallowRBF: x(8192x2048), centers(4096x2048), beta(4096), W(1000x4096), b(1000)
// out = (exp(-beta*||x-c||) @ W^T) / rowsum + b
//
// R5: split-K=2 gemm2 WITHOUT atomics (R4 lesson: 16.4M fp32 global atomics
// cost ~130 µs — cross-XCD RMW). z=0 stores raw acc to out; z=1 stores to a
// partial overlaid on dead xb; reduce_out does (out+P)*inv+bias (~16 µs).
// gemm1 frozen at its ~886 TF plateau.

#define BB 8192
#define DD 2048
#define CC 4096
#define KK 1000
#define KP 1024

typedef unsigned short u16;
typedef __bf16 bf16x8 __attribute__((ext_vector_type(8)));
typedef float f32x16 __attribute__((ext_vector_type(16)));

typedef const void __attribute__((address_space(1)))* gvp_t;
typedef void __attribute__((address_space(3)))* lvp_t;

__device__ __forceinline__ u16 f2bf(float f) {
  union { float f; unsigned u; } v; v.f = f;
  return (u16)((v.u + 0x7fffu + ((v.u >> 16) & 1u)) >> 16);  // RNE
}

// ---- prep: row norms (fp32) + bf16 casts of x and centers ----
__global__ void prep_norm_cast(const float* __restrict__ x, const float* __restrict__ cen,
                               u16* __restrict__ xb, u16* __restrict__ cb,
                               float* __restrict__ x2, float* __restrict__ c2) {
  int row = blockIdx.x;
  const float* src;
  u16* dst;
  float* nrm;
  if (row < BB) {
    src = x + (size_t)row * DD; dst = xb + (size_t)row * DD; nrm = x2 + row;
  } else {
    int r = row - BB;
    src = cen + (size_t)r * DD; dst = cb + (size_t)r * DD; nrm = c2 + r;
  }
  int t = threadIdx.x;
  float s = 0.f;
#pragma unroll
  for (int m = 0; m < 2; ++m) {
    int idx = t + 256 * m;
    float4 v = reinterpret_cast<const float4*>(src)[idx];
    s += v.x * v.x + v.y * v.y + v.z * v.z + v.w * v.w;
    reinterpret_cast<ushort4*>(dst)[idx] =
        make_ushort4(f2bf(v.x), f2bf(v.y), f2bf(v.z), f2bf(v.w));
  }
#pragma unroll
  for (int off = 1; off < 64; off <<= 1) s += __shfl_xor(s, off);
  __shared__ float red[4];
  if ((t & 63) == 0) red[t >> 6] = s;
  __syncthreads();
  if (t == 0) *nrm = red[0] + red[1] + red[2] + red[3];
}

// ---- prep: W cast to bf16, padded to 1024 rows (zeros) ----
__global__ void prep_wcast(const float* __restrict__ W, u16* __restrict__ wb) {
  int row = blockIdx.x;  // 0..1023
  int t = threadIdx.x;
  ushort4* dst = reinterpret_cast<ushort4*>(wb + (size_t)row * CC);
  if (row < KK) {
    const float4* src = reinterpret_cast<const float4*>(W + (size_t)row * CC);
#pragma unroll
    for (int m = 0; m < 4; ++m) {
      float4 v = src[t + 256 * m];
      dst[t + 256 * m] = make_ushort4(f2bf(v.x), f2bf(v.y), f2bf(v.z), f2bf(v.w));
    }
  } else {
#pragma unroll
    for (int m = 0; m < 4; ++m) dst[t + 256 * m] = make_ushort4(0, 0, 0, 0);
  }
}

// ---- GEMM1: 256x128 tile; epilogue e = exp(-beta*dist) -> Ebf ----
__global__ __launch_bounds__(256, 3)
void gemm1_rbf(const u16* __restrict__ Abf, const u16* __restrict__ Bbf,
               const float* __restrict__ x2, const float* __restrict__ c2,
               const float* __restrict__ beta, u16* __restrict__ Ebf) {
  constexpr int Kd = DD;
  __shared__ __align__(16) char smem[49152];  // A: 256x64 bf16 (32KB) + B: 128x64 (16KB)

  const int t = threadIdx.x;
  const int lane = t & 63;
  const int wave = t >> 6;
  const int wr = wave >> 1, wc = wave & 1;  // wave-tile: rows wr*128.., cols wc*64..
  const int l31 = lane & 31, khalf = lane >> 5;

  const int rowBase = blockIdx.y * 256;
  const int colBase = blockIdx.x * 128;

  f32x16 acc[4][2];
#pragma unroll
  for (int i = 0; i < 4; ++i)
#pragma unroll
    for (int j = 0; j < 2; ++j) acc[i][j] = 0.f;

  const int sr = t >> 3;
  const int fstage = ((t >> 3) & 7) ^ (((t >> 6) & 3) << 1);
  const int srcChunkOff = ((t & 7) ^ fstage) * 8;  // elements
  const u16* gA0 = Abf + (size_t)(rowBase + sr) * Kd + srcChunkOff;
  const u16* gB0 = Bbf + (size_t)(colBase + sr) * Kd + srcChunkOff;

  const int fv = (l31 & 7) ^ (((l31 >> 3) & 3) << 1);

  for (int kc = 0; kc < Kd; kc += 64) {
#pragma unroll
    for (int it = 0; it < 8; ++it) {
      const u16* ga = gA0 + (size_t)(32 * it) * Kd + kc;
      __builtin_amdgcn_global_load_lds((gvp_t)ga, (lvp_t)(smem + it * 4096 + t * 16), 16, 0, 0);
    }
#pragma unroll
    for (int it = 0; it < 4; ++it) {
      const u16* gb = gB0 + (size_t)(32 * it) * Kd + kc;
      __builtin_amdgcn_global_load_lds((gvp_t)gb, (lvp_t)(smem + 32768 + it * 4096 + t * 16), 16, 0, 0);
    }
    __syncthreads();
#pragma unroll
    for (int ks = 0; ks < 4; ++ks) {
      const int slot = ((ks * 2 + khalf) ^ fv) * 16;
      bf16x8 af[4], bfr[2];
#pragma unroll
      for (int i = 0; i < 4; ++i) {
        int r = wr * 128 + i * 32 + l31;
        af[i] = *(const bf16x8*)(smem + r * 128 + slot);
      }
#pragma unroll
      for (int j = 0; j < 2; ++j) {
        int r = wc * 64 + j * 32 + l31;
        bfr[j] = *(const bf16x8*)(smem + 32768 + r * 128 + slot);
      }
#pragma unroll
      for (int j = 0; j < 2; ++j)
#pragma unroll
        for (int i = 0; i < 4; ++i)
          acc[i][j] = __builtin_amdgcn_mfma_f32_32x32x16_bf16(af[i], bfr[j], acc[i][j], 0, 0, 0);
    }
    __syncthreads();
  }

  // epilogue: C/D layout col=lane&31, row=(reg&3)+8*(reg>>2)+4*(lane>>5)
  const int rbase = rowBase + wr * 128 + 4 * khalf;
  const int cbase = colBase + wc * 64;
  float c2v[2], bet[2];
  int gcol[2];
#pragma unroll
  for (int j = 0; j < 2; ++j) {
    gcol[j] = cbase + j * 32 + l31;
    c2v[j] = c2[gcol[j]];
    bet[j] = beta[gcol[j]];
  }
#pragma unroll
  for (int i = 0; i < 4; ++i) {
#pragma unroll
    for (int reg = 0; reg < 16; ++reg) {
      int grow = rbase + i * 32 + (reg & 3) + 8 * (reg >> 2);
      float x2v = x2[grow];
#pragma unroll
      for (int j = 0; j < 2; ++j) {
        float d = acc[i][j][reg];
        float sq = fmaxf(x2v + c2v[j] - 2.0f * d, 0.0f);
        float e = __expf(-bet[j] * __builtin_amdgcn_sqrtf(sq));
        Ebf[(size_t)grow * CC + gcol[j]] = f2bf(e);
      }
    }
  }
}

// ---- rowsum: one wave per row of Ebf ----
__global__ void rowsum_k(const u16* __restrict__ Ebf, float* __restrict__ rowsum) {
  const int lane = threadIdx.x & 63;
  const int row = blockIdx.x * 4 + (threadIdx.x >> 6);
  const uint4* p = reinterpret_cast<const uint4*>(Ebf + (size_t)row * CC);
  float s = 0.f;
#pragma unroll
  for (int it = 0; it < 8; ++it) {
    uint4 v = p[lane + 64 * it];
    unsigned w[4] = {v.x, v.y, v.z, v.w};
#pragma unroll
    for (int q = 0; q < 4; ++q) {
      union { unsigned u; float f; } lo, hi;
      lo.u = w[q] << 16;
      hi.u = w[q] & 0xffff0000u;
      s += lo.f + hi.f;
    }
  }
#pragma unroll
  for (int off = 1; off < 64; off <<= 1) s += __shfl_xor(s, off);
  if (lane == 0) rowsum[row] = s;
}

// ---- GEMM2: raw partial E@W^T; z=0 -> out (stride KK), z=1 -> P (stride KP) ----
__global__ __launch_bounds__(256, 3)
void gemm2_out(const u16* __restrict__ Ebf, const u16* __restrict__ Wbf,
               float* __restrict__ out, float* __restrict__ P) {
  constexpr int Kd = CC;
  __shared__ __align__(16) char smem[49152];  // A: 256x64 (32KB) + B: 128x64 (16KB)

  const int t = threadIdx.x;
  const int lane = t & 63;
  const int wave = t >> 6;
  const int wr = wave >> 1, wc = wave & 1;
  const int l31 = lane & 31, khalf = lane >> 5;

  const int rowBase = blockIdx.y * 256;
  const int colBase = blockIdx.x * 128;
  const int kBase = blockIdx.z * (CC / 2);

  f32x16 acc[4][2];
#pragma unroll
  for (int i = 0; i < 4; ++i)
#pragma unroll
    for (int j = 0; j < 2; ++j) acc[i][j] = 0.f;

  const int sr = t >> 3;
  const int fstage = ((t >> 3) & 7) ^ (((t >> 6) & 3) << 1);
  const int srcChunkOff = ((t & 7) ^ fstage) * 8;
  const u16* gA0 = Ebf + (size_t)(rowBase + sr) * Kd + kBase + srcChunkOff;
  const u16* gB0 = Wbf + (size_t)(colBase + sr) * Kd + kBase + srcChunkOff;
  const int fv = (l31 & 7) ^ (((l31 >> 3) & 3) << 1);

  for (int kc = 0; kc < CC / 2; kc += 64) {
#pragma unroll
    for (int it = 0; it < 8; ++it) {
      const u16* ga = gA0 + (size_t)(32 * it) * Kd + kc;
      __builtin_amdgcn_global_load_lds((gvp_t)ga, (lvp_t)(smem + it * 4096 + t * 16), 16, 0, 0);
    }
#pragma unroll
    for (int it = 0; it < 4; ++it) {
      const u16* gb = gB0 + (size_t)(32 * it) * Kd + kc;
      __builtin_amdgcn_global_load_lds((gvp_t)gb, (lvp_t)(smem + 32768 + it * 4096 + t * 16), 16, 0, 0);
    }
    __syncthreads();
#pragma unroll
    for (int ks = 0; ks < 4; ++ks) {
      const int slot = ((ks * 2 + khalf) ^ fv) * 16;
      bf16x8 af[4], bfr[2];
#pragma unroll
      for (int i = 0; i < 4; ++i) {
        int r = wr * 128 + i * 32 + l31;
        af[i] = *(const bf16x8*)(smem + r * 128 + slot);
      }
#pragma unroll
      for (int j = 0; j < 2; ++j) {
        int r = wc * 64 + j * 32 + l31;
        bfr[j] = *(const bf16x8*)(smem + 32768 + r * 128 + slot);
      }
#pragma unroll
      for (int j = 0; j < 2; ++j)
#pragma unroll
        for (int i = 0; i < 4; ++i)
          acc[i][j] = __builtin_amdgcn_mfma_f32_32x32x16_bf16(af[i], bfr[j], acc[i][j], 0, 0, 0);
    }
    __syncthreads();
  }

  const int rbase = rowBase + wr * 128 + 4 * khalf;
  const int cbase = colBase + wc * 64;
  int gcol[2];
#pragma unroll
  for (int j = 0; j < 2; ++j) gcol[j] = cbase + j * 32 + l31;

  if (blockIdx.z == 0) {
#pragma unroll
    for (int i = 0; i < 4; ++i)
#pragma unroll
      for (int reg = 0; reg < 16; ++reg) {
        int grow = rbase + i * 32 + (reg & 3) + 8 * (reg >> 2);
#pragma unroll
        for (int j = 0; j < 2; ++j)
          if (gcol[j] < KK) out[(size_t)grow * KK + gcol[j]] = acc[i][j][reg];
      }
  } else {
#pragma unroll
    for (int i = 0; i < 4; ++i)
#pragma unroll
      for (int reg = 0; reg < 16; ++reg) {
        int grow = rbase + i * 32 + (reg & 3) + 8 * (reg >> 2);
#pragma unroll
        for (int j = 0; j < 2; ++j)
          P[(size_t)grow * KP + gcol[j]] = acc[i][j][reg];
      }
  }
}

// ---- reduce: out = (out + P) / rowsum + bias ----
__global__ void reduce_out(float* __restrict__ out, const float* __restrict__ P,
                           const float* __restrict__ rowsum, const float* __restrict__ bias) {
  const int row = blockIdx.x;
  const int t = threadIdx.x;
  if (t < KK / 4) {
    const float inv = 1.0f / rowsum[row];
    float4 o = reinterpret_cast<const float4*>(out + (size_t)row * KK)[t];
    float4 p = reinterpret_cast<const float4*>(P + (size_t)row * KP)[t];
    float4 bv = reinterpret_cast<const float4*>(bias)[t];
    float4 r;
    r.x = (o.x + p.x) * inv + bv.x;
    r.y = (o.y + p.y) * inv + bv.y;
    r.z = (o.z + p.z) * inv + bv.z;
    r.w = (o.w + p.w) * inv + bv.w;
    reinterpret_cast<float4*>(out + (size_t)row * KK)[t] = r;
  }
}

// ---- workspace layout (bytes) ----
#define OFF_XB 0u                    // 8192*2048*2 = 33554432 (xb; reused as P after gemm1)
#define OFF_CB 33554432u             // 4096*2048*2 = 16777216
#define OFF_WB 50331648u             // 1024*4096*2 = 8388608
#define OFF_EB 58720256u             // 8192*4096*2 = 67108864
#define OFF_X2 125829120u            // 8192*4
#define OFF_C2 125861888u            // 4096*4
#define OFF_RS 125878272u            // 8192*4
// P (split-K partial, 8192*1024*4 = 33554432) overlays OFF_XB — xb dead after gemm1.

extern "C" void kernel_launch(void* const* d_in, const int* in_sizes, int n_in,
                              void* d_out, int out_size, void* d_ws, size_t ws_size,
                              hipStream_t stream) {
  const float* x = (const float*)d_in[0];
  const float* cen = (const float*)d_in[1];
  const float* beta = (const float*)d_in[2];
  const float* W = (const float*)d_in[3];
  const float* bias = (const float*)d_in[4];
  float* out = (float*)d_out;
  char* ws = (char*)d_ws;

  u16* xb = (u16*)(ws + OFF_XB);
  u16* cb = (u16*)(ws + OFF_CB);
  u16* wb = (u16*)(ws + OFF_WB);
  u16* eb = (u16*)(ws + OFF_EB);
  float* x2 = (float*)(ws + OFF_X2);
  float* c2 = (float*)(ws + OFF_C2);
  float* rowsum = (float*)(ws + OFF_RS);
  float* P = (float*)(ws + OFF_XB);  // overlay on dead xb

  prep_norm_cast<<<BB + CC, 256, 0, stream>>>(x, cen, xb, cb, x2, c2);
  prep_wcast<<<KP, 256, 0, stream>>>(W, wb);
  gemm1_rbf<<<dim3(CC / 128, BB / 256), 256, 0, stream>>>(xb, cb, x2, c2, beta, eb);
  rowsum_k<<<BB / 4, 256, 0, stream>>>(eb, rowsum);
  gemm2_out<<<dim3(KP / 128, BB / 256, 2), 256, 0, stream>>>(eb, wb, out, P);
  reduce_out<<<BB, 256, 0, stream>>>(out, P, rowsum, bias);
}

// Round 6
// 412.312 us; speedup vs baseline: 1.0695x; 1.0057x over previous
//
#include <hip/hip_runtime.h>

// ShallowRBF: x(8192x2048), centers(4096x2048), beta(4096), W(1000x4096), b(1000)
// out = (exp(-beta*||x-c||) @ W^T) / rowsum + b
//
// R6: gemm2 = 128x128 tile + split-K=2 -> 1024 blocks, 32KB LDS, 4 blocks/CU
// (R5 lesson: 256x128+splitK gave only 512 blocks = 2/CU — barrier drain
// exposed; oversubscription, not inner-loop ratio, is what the ~880 TF
// plateau needs). Partial stores + reduce (no atomics — R4 lesson).
// gemm1 frozen at its ~886 TF plateau.

#define BB 8192
#define DD 2048
#define CC 4096
#define KK 1000
#define KP 1024

typedef unsigned short u16;
typedef __bf16 bf16x8 __attribute__((ext_vector_type(8)));
typedef float f32x16 __attribute__((ext_vector_type(16)));

typedef const void __attribute__((address_space(1)))* gvp_t;
typedef void __attribute__((address_space(3)))* lvp_t;

__device__ __forceinline__ u16 f2bf(float f) {
  union { float f; unsigned u; } v; v.f = f;
  return (u16)((v.u + 0x7fffu + ((v.u >> 16) & 1u)) >> 16);  // RNE
}

// ---- prep: row norms (fp32) + bf16 casts of x and centers ----
__global__ void prep_norm_cast(const float* __restrict__ x, const float* __restrict__ cen,
                               u16* __restrict__ xb, u16* __restrict__ cb,
                               float* __restrict__ x2, float* __restrict__ c2) {
  int row = blockIdx.x;
  const float* src;
  u16* dst;
  float* nrm;
  if (row < BB) {
    src = x + (size_t)row * DD; dst = xb + (size_t)row * DD; nrm = x2 + row;
  } else {
    int r = row - BB;
    src = cen + (size_t)r * DD; dst = cb + (size_t)r * DD; nrm = c2 + r;
  }
  int t = threadIdx.x;
  float s = 0.f;
#pragma unroll
  for (int m = 0; m < 2; ++m) {
    int idx = t + 256 * m;
    float4 v = reinterpret_cast<const float4*>(src)[idx];
    s += v.x * v.x + v.y * v.y + v.z * v.z + v.w * v.w;
    reinterpret_cast<ushort4*>(dst)[idx] =
        make_ushort4(f2bf(v.x), f2bf(v.y), f2bf(v.z), f2bf(v.w));
  }
#pragma unroll
  for (int off = 1; off < 64; off <<= 1) s += __shfl_xor(s, off);
  __shared__ float red[4];
  if ((t & 63) == 0) red[t >> 6] = s;
  __syncthreads();
  if (t == 0) *nrm = red[0] + red[1] + red[2] + red[3];
}

// ---- prep: W cast to bf16, padded to 1024 rows (zeros) ----
__global__ void prep_wcast(const float* __restrict__ W, u16* __restrict__ wb) {
  int row = blockIdx.x;  // 0..1023
  int t = threadIdx.x;
  ushort4* dst = reinterpret_cast<ushort4*>(wb + (size_t)row * CC);
  if (row < KK) {
    const float4* src = reinterpret_cast<const float4*>(W + (size_t)row * CC);
#pragma unroll
    for (int m = 0; m < 4; ++m) {
      float4 v = src[t + 256 * m];
      dst[t + 256 * m] = make_ushort4(f2bf(v.x), f2bf(v.y), f2bf(v.z), f2bf(v.w));
    }
  } else {
#pragma unroll
    for (int m = 0; m < 4; ++m) dst[t + 256 * m] = make_ushort4(0, 0, 0, 0);
  }
}

// ---- GEMM1: 256x128 tile; epilogue e = exp(-beta*dist) -> Ebf ----
__global__ __launch_bounds__(256, 3)
void gemm1_rbf(const u16* __restrict__ Abf, const u16* __restrict__ Bbf,
               const float* __restrict__ x2, const float* __restrict__ c2,
               const float* __restrict__ beta, u16* __restrict__ Ebf) {
  constexpr int Kd = DD;
  __shared__ __align__(16) char smem[49152];  // A: 256x64 bf16 (32KB) + B: 128x64 (16KB)

  const int t = threadIdx.x;
  const int lane = t & 63;
  const int wave = t >> 6;
  const int wr = wave >> 1, wc = wave & 1;  // wave-tile: rows wr*128.., cols wc*64..
  const int l31 = lane & 31, khalf = lane >> 5;

  const int rowBase = blockIdx.y * 256;
  const int colBase = blockIdx.x * 128;

  f32x16 acc[4][2];
#pragma unroll
  for (int i = 0; i < 4; ++i)
#pragma unroll
    for (int j = 0; j < 2; ++j) acc[i][j] = 0.f;

  const int sr = t >> 3;
  const int fstage = ((t >> 3) & 7) ^ (((t >> 6) & 3) << 1);
  const int srcChunkOff = ((t & 7) ^ fstage) * 8;  // elements
  const u16* gA0 = Abf + (size_t)(rowBase + sr) * Kd + srcChunkOff;
  const u16* gB0 = Bbf + (size_t)(colBase + sr) * Kd + srcChunkOff;

  const int fv = (l31 & 7) ^ (((l31 >> 3) & 3) << 1);

  for (int kc = 0; kc < Kd; kc += 64) {
#pragma unroll
    for (int it = 0; it < 8; ++it) {
      const u16* ga = gA0 + (size_t)(32 * it) * Kd + kc;
      __builtin_amdgcn_global_load_lds((gvp_t)ga, (lvp_t)(smem + it * 4096 + t * 16), 16, 0, 0);
    }
#pragma unroll
    for (int it = 0; it < 4; ++it) {
      const u16* gb = gB0 + (size_t)(32 * it) * Kd + kc;
      __builtin_amdgcn_global_load_lds((gvp_t)gb, (lvp_t)(smem + 32768 + it * 4096 + t * 16), 16, 0, 0);
    }
    __syncthreads();
#pragma unroll
    for (int ks = 0; ks < 4; ++ks) {
      const int slot = ((ks * 2 + khalf) ^ fv) * 16;
      bf16x8 af[4], bfr[2];
#pragma unroll
      for (int i = 0; i < 4; ++i) {
        int r = wr * 128 + i * 32 + l31;
        af[i] = *(const bf16x8*)(smem + r * 128 + slot);
      }
#pragma unroll
      for (int j = 0; j < 2; ++j) {
        int r = wc * 64 + j * 32 + l31;
        bfr[j] = *(const bf16x8*)(smem + 32768 + r * 128 + slot);
      }
#pragma unroll
      for (int j = 0; j < 2; ++j)
#pragma unroll
        for (int i = 0; i < 4; ++i)
          acc[i][j] = __builtin_amdgcn_mfma_f32_32x32x16_bf16(af[i], bfr[j], acc[i][j], 0, 0, 0);
    }
    __syncthreads();
  }

  // epilogue: C/D layout col=lane&31, row=(reg&3)+8*(reg>>2)+4*(lane>>5)
  const int rbase = rowBase + wr * 128 + 4 * khalf;
  const int cbase = colBase + wc * 64;
  float c2v[2], bet[2];
  int gcol[2];
#pragma unroll
  for (int j = 0; j < 2; ++j) {
    gcol[j] = cbase + j * 32 + l31;
    c2v[j] = c2[gcol[j]];
    bet[j] = beta[gcol[j]];
  }
#pragma unroll
  for (int i = 0; i < 4; ++i) {
#pragma unroll
    for (int reg = 0; reg < 16; ++reg) {
      int grow = rbase + i * 32 + (reg & 3) + 8 * (reg >> 2);
      float x2v = x2[grow];
#pragma unroll
      for (int j = 0; j < 2; ++j) {
        float d = acc[i][j][reg];
        float sq = fmaxf(x2v + c2v[j] - 2.0f * d, 0.0f);
        float e = __expf(-bet[j] * __builtin_amdgcn_sqrtf(sq));
        Ebf[(size_t)grow * CC + gcol[j]] = f2bf(e);
      }
    }
  }
}

// ---- rowsum: one wave per row of Ebf ----
__global__ void rowsum_k(const u16* __restrict__ Ebf, float* __restrict__ rowsum) {
  const int lane = threadIdx.x & 63;
  const int row = blockIdx.x * 4 + (threadIdx.x >> 6);
  const uint4* p = reinterpret_cast<const uint4*>(Ebf + (size_t)row * CC);
  float s = 0.f;
#pragma unroll
  for (int it = 0; it < 8; ++it) {
    uint4 v = p[lane + 64 * it];
    unsigned w[4] = {v.x, v.y, v.z, v.w};
#pragma unroll
    for (int q = 0; q < 4; ++q) {
      union { unsigned u; float f; } lo, hi;
      lo.u = w[q] << 16;
      hi.u = w[q] & 0xffff0000u;
      s += lo.f + hi.f;
    }
  }
#pragma unroll
  for (int off = 1; off < 64; off <<= 1) s += __shfl_xor(s, off);
  if (lane == 0) rowsum[row] = s;
}

// ---- GEMM2: raw partial E@W^T; 128x128 tile, split-K=2; z=0 -> out, z=1 -> P ----
__global__ __launch_bounds__(256, 4)
void gemm2_out(const u16* __restrict__ Ebf, const u16* __restrict__ Wbf,
               float* __restrict__ out, float* __restrict__ P) {
  constexpr int Kd = CC;
  __shared__ __align__(16) char smem[32768];  // A: 128x64 (16KB) + B: 128x64 (16KB)

  const int t = threadIdx.x;
  const int lane = t & 63;
  const int wave = t >> 6;
  const int wr = wave >> 1, wc = wave & 1;
  const int l31 = lane & 31, khalf = lane >> 5;

  const int rowBase = blockIdx.y * 128;
  const int colBase = blockIdx.x * 128;
  const int kBase = blockIdx.z * (CC / 2);

  f32x16 acc[2][2];
#pragma unroll
  for (int i = 0; i < 2; ++i)
#pragma unroll
    for (int j = 0; j < 2; ++j) acc[i][j] = 0.f;

  const int sr = t >> 3;
  const int fstage = ((t >> 3) & 7) ^ (((t >> 6) & 3) << 1);
  const int srcChunkOff = ((t & 7) ^ fstage) * 8;
  const u16* gA0 = Ebf + (size_t)(rowBase + sr) * Kd + kBase + srcChunkOff;
  const u16* gB0 = Wbf + (size_t)(colBase + sr) * Kd + kBase + srcChunkOff;
  const int fv = (l31 & 7) ^ (((l31 >> 3) & 3) << 1);

  for (int kc = 0; kc < CC / 2; kc += 64) {
#pragma unroll
    for (int it = 0; it < 4; ++it) {
      const u16* ga = gA0 + (size_t)(32 * it) * Kd + kc;
      __builtin_amdgcn_global_load_lds((gvp_t)ga, (lvp_t)(smem + it * 4096 + t * 16), 16, 0, 0);
    }
#pragma unroll
    for (int it = 0; it < 4; ++it) {
      const u16* gb = gB0 + (size_t)(32 * it) * Kd + kc;
      __builtin_amdgcn_global_load_lds((gvp_t)gb, (lvp_t)(smem + 16384 + it * 4096 + t * 16), 16, 0, 0);
    }
    __syncthreads();
#pragma unroll
    for (int ks = 0; ks < 4; ++ks) {
      const int slot = ((ks * 2 + khalf) ^ fv) * 16;
      bf16x8 af[2], bfr[2];
#pragma unroll
      for (int i = 0; i < 2; ++i) {
        int r = wr * 64 + i * 32 + l31;
        af[i] = *(const bf16x8*)(smem + r * 128 + slot);
      }
#pragma unroll
      for (int j = 0; j < 2; ++j) {
        int r = wc * 64 + j * 32 + l31;
        bfr[j] = *(const bf16x8*)(smem + 16384 + r * 128 + slot);
      }
#pragma unroll
      for (int j = 0; j < 2; ++j)
#pragma unroll
        for (int i = 0; i < 2; ++i)
          acc[i][j] = __builtin_amdgcn_mfma_f32_32x32x16_bf16(af[i], bfr[j], acc[i][j], 0, 0, 0);
    }
    __syncthreads();
  }

  const int rbase = rowBase + wr * 64 + 4 * khalf;
  const int cbase = colBase + wc * 64;
  int gcol[2];
#pragma unroll
  for (int j = 0; j < 2; ++j) gcol[j] = cbase + j * 32 + l31;

  if (blockIdx.z == 0) {
#pragma unroll
    for (int i = 0; i < 2; ++i)
#pragma unroll
      for (int reg = 0; reg < 16; ++reg) {
        int grow = rbase + i * 32 + (reg & 3) + 8 * (reg >> 2);
#pragma unroll
        for (int j = 0; j < 2; ++j)
          if (gcol[j] < KK) out[(size_t)grow * KK + gcol[j]] = acc[i][j][reg];
      }
  } else {
#pragma unroll
    for (int i = 0; i < 2; ++i)
#pragma unroll
      for (int reg = 0; reg < 16; ++reg) {
        int grow = rbase + i * 32 + (reg & 3) + 8 * (reg >> 2);
#pragma unroll
        for (int j = 0; j < 2; ++j)
          P[(size_t)grow * KP + gcol[j]] = acc[i][j][reg];
      }
  }
}

// ---- reduce: out = (out + P) / rowsum + bias ----
__global__ void reduce_out(float* __restrict__ out, const float* __restrict__ P,
                           const float* __restrict__ rowsum, const float* __restrict__ bias) {
  const int row = blockIdx.x;
  const int t = threadIdx.x;
  if (t < KK / 4) {
    const float inv = 1.0f / rowsum[row];
    float4 o = reinterpret_cast<const float4*>(out + (size_t)row * KK)[t];
    float4 p = reinterpret_cast<const float4*>(P + (size_t)row * KP)[t];
    float4 bv = reinterpret_cast<const float4*>(bias)[t];
    float4 r;
    r.x = (o.x + p.x) * inv + bv.x;
    r.y = (o.y + p.y) * inv + bv.y;
    r.z = (o.z + p.z) * inv + bv.z;
    r.w = (o.w + p.w) * inv + bv.w;
    reinterpret_cast<float4*>(out + (size_t)row * KK)[t] = r;
  }
}

// ---- workspace layout (bytes) ----
#define OFF_XB 0u                    // 8192*2048*2 = 33554432 (xb; reused as P after gemm1)
#define OFF_CB 33554432u             // 4096*2048*2 = 16777216
#define OFF_WB 50331648u             // 1024*4096*2 = 8388608
#define OFF_EB 58720256u             // 8192*4096*2 = 67108864
#define OFF_X2 125829120u            // 8192*4
#define OFF_C2 125861888u            // 4096*4
#define OFF_RS 125878272u            // 8192*4
// P (split-K partial, 8192*1024*4 = 33554432) overlays OFF_XB — xb dead after gemm1.

extern "C" void kernel_launch(void* const* d_in, const int* in_sizes, int n_in,
                              void* d_out, int out_size, void* d_ws, size_t ws_size,
                              hipStream_t stream) {
  const float* x = (const float*)d_in[0];
  const float* cen = (const float*)d_in[1];
  const float* beta = (const float*)d_in[2];
  const float* W = (const float*)d_in[3];
  const float* bias = (const float*)d_in[4];
  float* out = (float*)d_out;
  char* ws = (char*)d_ws;

  u16* xb = (u16*)(ws + OFF_XB);
  u16* cb = (u16*)(ws + OFF_CB);
  u16* wb = (u16*)(ws + OFF_WB);
  u16* eb = (u16*)(ws + OFF_EB);
  float* x2 = (float*)(ws + OFF_X2);
  float* c2 = (float*)(ws + OFF_C2);
  float* rowsum = (float*)(ws + OFF_RS);
  float* P = (float*)(ws + OFF_XB);  // overlay on dead xb

  prep_norm_cast<<<BB + CC, 256, 0, stream>>>(x, cen, xb, cb, x2, c2);
  prep_wcast<<<KP, 256, 0, stream>>>(W, wb);
  gemm1_rbf<<<dim3(CC / 128, BB / 256), 256, 0, stream>>>(xb, cb, x2, c2, beta, eb);
  rowsum_k<<<BB / 4, 256, 0, stream>>>(eb, rowsum);
  gemm2_out<<<dim3(KP / 128, BB / 128, 2), 256, 0, stream>>>(eb, wb, out, P);
  reduce_out<<<BB, 256, 0, stream>>>(out, P, rowsum, bias);
}

// Round 7
// 398.714 us; speedup vs baseline: 1.1059x; 1.0341x over previous
//
#include <hip/hip_runtime.h>

// ShallowRBF: x(8192x2048), centers(4096x2048), beta(4096), W(1000x4096), b(1000)
// out = (exp(-beta*||x-c||) @ W^T) / rowsum + b
//
// R7: rowsum for FREE — W_pad row 1000 := ones, so gemm2's (discarded) col
// 1000 = rowsum(e). rowsum_k deleted; preps merged. gemm1 frozen (886 TF
// bf16 plateau; fp8 numerically dead for distance: 6.25% rel err -> 5e-4
// out err >> 5e-5 threshold). NOTE R6 session was clock-throttled ~20%
// (identical gemm1 code+counters, 25% more time) — compare via gemm1 yardstick.

#define BB 8192
#define DD 2048
#define CC 4096
#define KK 1000
#define KP 1024

typedef unsigned short u16;
typedef __bf16 bf16x8 __attribute__((ext_vector_type(8)));
typedef float f32x16 __attribute__((ext_vector_type(16)));

typedef const void __attribute__((address_space(1)))* gvp_t;
typedef void __attribute__((address_space(3)))* lvp_t;

__device__ __forceinline__ u16 f2bf(float f) {
  union { float f; unsigned u; } v; v.f = f;
  return (u16)((v.u + 0x7fffu + ((v.u >> 16) & 1u)) >> 16);  // RNE
}

// ---- prep: x/centers norms + bf16 casts, and W cast padded to 1024 rows
//      (row 1000 = ones -> gemm2 col 1000 computes rowsum; rows 1001+ = 0) ----
__global__ void prep_all(const float* __restrict__ x, const float* __restrict__ cen,
                         const float* __restrict__ W,
                         u16* __restrict__ xb, u16* __restrict__ cb, u16* __restrict__ wb,
                         float* __restrict__ x2, float* __restrict__ c2) {
  int row = blockIdx.x;
  int t = threadIdx.x;
  if (row >= BB + CC) {  // W branch: rows of length CC=4096
    int r = row - BB - CC;  // 0..1023
    ushort4* dst = reinterpret_cast<ushort4*>(wb + (size_t)r * CC);
    if (r < KK) {
      const float4* src = reinterpret_cast<const float4*>(W + (size_t)r * CC);
#pragma unroll
      for (int m = 0; m < 4; ++m) {
        float4 v = src[t + 256 * m];
        dst[t + 256 * m] = make_ushort4(f2bf(v.x), f2bf(v.y), f2bf(v.z), f2bf(v.w));
      }
    } else {
      u16 fill = (r == KK) ? (u16)0x3F80 : (u16)0;  // ones row / zero rows
#pragma unroll
      for (int m = 0; m < 4; ++m) dst[t + 256 * m] = make_ushort4(fill, fill, fill, fill);
    }
    return;
  }
  const float* src;
  u16* dst;
  float* nrm;
  if (row < BB) {
    src = x + (size_t)row * DD; dst = xb + (size_t)row * DD; nrm = x2 + row;
  } else {
    int r = row - BB;
    src = cen + (size_t)r * DD; dst = cb + (size_t)r * DD; nrm = c2 + r;
  }
  float s = 0.f;
#pragma unroll
  for (int m = 0; m < 2; ++m) {
    int idx = t + 256 * m;
    float4 v = reinterpret_cast<const float4*>(src)[idx];
    s += v.x * v.x + v.y * v.y + v.z * v.z + v.w * v.w;
    reinterpret_cast<ushort4*>(dst)[idx] =
        make_ushort4(f2bf(v.x), f2bf(v.y), f2bf(v.z), f2bf(v.w));
  }
#pragma unroll
  for (int off = 1; off < 64; off <<= 1) s += __shfl_xor(s, off);
  __shared__ float red[4];
  if ((t & 63) == 0) red[t >> 6] = s;
  __syncthreads();
  if (t == 0) *nrm = red[0] + red[1] + red[2] + red[3];
}

// ---- GEMM1: 256x128 tile; epilogue e = exp(-beta*dist) -> Ebf ----
__global__ __launch_bounds__(256, 3)
void gemm1_rbf(const u16* __restrict__ Abf, const u16* __restrict__ Bbf,
               const float* __restrict__ x2, const float* __restrict__ c2,
               const float* __restrict__ beta, u16* __restrict__ Ebf) {
  constexpr int Kd = DD;
  __shared__ __align__(16) char smem[49152];  // A: 256x64 bf16 (32KB) + B: 128x64 (16KB)

  const int t = threadIdx.x;
  const int lane = t & 63;
  const int wave = t >> 6;
  const int wr = wave >> 1, wc = wave & 1;  // wave-tile: rows wr*128.., cols wc*64..
  const int l31 = lane & 31, khalf = lane >> 5;

  const int rowBase = blockIdx.y * 256;
  const int colBase = blockIdx.x * 128;

  f32x16 acc[4][2];
#pragma unroll
  for (int i = 0; i < 4; ++i)
#pragma unroll
    for (int j = 0; j < 2; ++j) acc[i][j] = 0.f;

  const int sr = t >> 3;
  const int fstage = ((t >> 3) & 7) ^ (((t >> 6) & 3) << 1);
  const int srcChunkOff = ((t & 7) ^ fstage) * 8;  // elements
  const u16* gA0 = Abf + (size_t)(rowBase + sr) * Kd + srcChunkOff;
  const u16* gB0 = Bbf + (size_t)(colBase + sr) * Kd + srcChunkOff;

  const int fv = (l31 & 7) ^ (((l31 >> 3) & 3) << 1);

  for (int kc = 0; kc < Kd; kc += 64) {
#pragma unroll
    for (int it = 0; it < 8; ++it) {
      const u16* ga = gA0 + (size_t)(32 * it) * Kd + kc;
      __builtin_amdgcn_global_load_lds((gvp_t)ga, (lvp_t)(smem + it * 4096 + t * 16), 16, 0, 0);
    }
#pragma unroll
    for (int it = 0; it < 4; ++it) {
      const u16* gb = gB0 + (size_t)(32 * it) * Kd + kc;
      __builtin_amdgcn_global_load_lds((gvp_t)gb, (lvp_t)(smem + 32768 + it * 4096 + t * 16), 16, 0, 0);
    }
    __syncthreads();
#pragma unroll
    for (int ks = 0; ks < 4; ++ks) {
      const int slot = ((ks * 2 + khalf) ^ fv) * 16;
      bf16x8 af[4], bfr[2];
#pragma unroll
      for (int i = 0; i < 4; ++i) {
        int r = wr * 128 + i * 32 + l31;
        af[i] = *(const bf16x8*)(smem + r * 128 + slot);
      }
#pragma unroll
      for (int j = 0; j < 2; ++j) {
        int r = wc * 64 + j * 32 + l31;
        bfr[j] = *(const bf16x8*)(smem + 32768 + r * 128 + slot);
      }
#pragma unroll
      for (int j = 0; j < 2; ++j)
#pragma unroll
        for (int i = 0; i < 4; ++i)
          acc[i][j] = __builtin_amdgcn_mfma_f32_32x32x16_bf16(af[i], bfr[j], acc[i][j], 0, 0, 0);
    }
    __syncthreads();
  }

  // epilogue: C/D layout col=lane&31, row=(reg&3)+8*(reg>>2)+4*(lane>>5)
  const int rbase = rowBase + wr * 128 + 4 * khalf;
  const int cbase = colBase + wc * 64;
  float c2v[2], bet[2];
  int gcol[2];
#pragma unroll
  for (int j = 0; j < 2; ++j) {
    gcol[j] = cbase + j * 32 + l31;
    c2v[j] = c2[gcol[j]];
    bet[j] = beta[gcol[j]];
  }
#pragma unroll
  for (int i = 0; i < 4; ++i) {
#pragma unroll
    for (int reg = 0; reg < 16; ++reg) {
      int grow = rbase + i * 32 + (reg & 3) + 8 * (reg >> 2);
      float x2v = x2[grow];
#pragma unroll
      for (int j = 0; j < 2; ++j) {
        float d = acc[i][j][reg];
        float sq = fmaxf(x2v + c2v[j] - 2.0f * d, 0.0f);
        float e = __expf(-bet[j] * __builtin_amdgcn_sqrtf(sq));
        Ebf[(size_t)grow * CC + gcol[j]] = f2bf(e);
      }
    }
  }
}

// ---- GEMM2: raw partial E@W_pad^T; 128x128 tile, split-K=2.
//      z=0: cols<KK -> out, col KK -> rs0 (rowsum partial). z=1: all -> P. ----
__global__ __launch_bounds__(256, 4)
void gemm2_out(const u16* __restrict__ Ebf, const u16* __restrict__ Wbf,
               float* __restrict__ out, float* __restrict__ P, float* __restrict__ rs0) {
  constexpr int Kd = CC;
  __shared__ __align__(16) char smem[32768];  // A: 128x64 (16KB) + B: 128x64 (16KB)

  const int t = threadIdx.x;
  const int lane = t & 63;
  const int wave = t >> 6;
  const int wr = wave >> 1, wc = wave & 1;
  const int l31 = lane & 31, khalf = lane >> 5;

  const int rowBase = blockIdx.y * 128;
  const int colBase = blockIdx.x * 128;
  const int kBase = blockIdx.z * (CC / 2);

  f32x16 acc[2][2];
#pragma unroll
  for (int i = 0; i < 2; ++i)
#pragma unroll
    for (int j = 0; j < 2; ++j) acc[i][j] = 0.f;

  const int sr = t >> 3;
  const int fstage = ((t >> 3) & 7) ^ (((t >> 6) & 3) << 1);
  const int srcChunkOff = ((t & 7) ^ fstage) * 8;
  const u16* gA0 = Ebf + (size_t)(rowBase + sr) * Kd + kBase + srcChunkOff;
  const u16* gB0 = Wbf + (size_t)(colBase + sr) * Kd + kBase + srcChunkOff;
  const int fv = (l31 & 7) ^ (((l31 >> 3) & 3) << 1);

  for (int kc = 0; kc < CC / 2; kc += 64) {
#pragma unroll
    for (int it = 0; it < 4; ++it) {
      const u16* ga = gA0 + (size_t)(32 * it) * Kd + kc;
      __builtin_amdgcn_global_load_lds((gvp_t)ga, (lvp_t)(smem + it * 4096 + t * 16), 16, 0, 0);
    }
#pragma unroll
    for (int it = 0; it < 4; ++it) {
      const u16* gb = gB0 + (size_t)(32 * it) * Kd + kc;
      __builtin_amdgcn_global_load_lds((gvp_t)gb, (lvp_t)(smem + 16384 + it * 4096 + t * 16), 16, 0, 0);
    }
    __syncthreads();
#pragma unroll
    for (int ks = 0; ks < 4; ++ks) {
      const int slot = ((ks * 2 + khalf) ^ fv) * 16;
      bf16x8 af[2], bfr[2];
#pragma unroll
      for (int i = 0; i < 2; ++i) {
        int r = wr * 64 + i * 32 + l31;
        af[i] = *(const bf16x8*)(smem + r * 128 + slot);
      }
#pragma unroll
      for (int j = 0; j < 2; ++j) {
        int r = wc * 64 + j * 32 + l31;
        bfr[j] = *(const bf16x8*)(smem + 16384 + r * 128 + slot);
      }
#pragma unroll
      for (int j = 0; j < 2; ++j)
#pragma unroll
        for (int i = 0; i < 2; ++i)
          acc[i][j] = __builtin_amdgcn_mfma_f32_32x32x16_bf16(af[i], bfr[j], acc[i][j], 0, 0, 0);
    }
    __syncthreads();
  }

  const int rbase = rowBase + wr * 64 + 4 * khalf;
  const int cbase = colBase + wc * 64;
  int gcol[2];
#pragma unroll
  for (int j = 0; j < 2; ++j) gcol[j] = cbase + j * 32 + l31;

  if (blockIdx.z == 0) {
#pragma unroll
    for (int i = 0; i < 2; ++i)
#pragma unroll
      for (int reg = 0; reg < 16; ++reg) {
        int grow = rbase + i * 32 + (reg & 3) + 8 * (reg >> 2);
#pragma unroll
        for (int j = 0; j < 2; ++j) {
          if (gcol[j] < KK) out[(size_t)grow * KK + gcol[j]] = acc[i][j][reg];
          else if (gcol[j] == KK) rs0[grow] = acc[i][j][reg];  // rowsum partial 0
        }
      }
  } else {
#pragma unroll
    for (int i = 0; i < 2; ++i)
#pragma unroll
      for (int reg = 0; reg < 16; ++reg) {
        int grow = rbase + i * 32 + (reg & 3) + 8 * (reg >> 2);
#pragma unroll
        for (int j = 0; j < 2; ++j)
          P[(size_t)grow * KP + gcol[j]] = acc[i][j][reg];
      }
  }
}

// ---- reduce: out = (out + P) / (rs0 + P[:,KK]) + bias ----
__global__ void reduce_out(float* __restrict__ out, const float* __restrict__ P,
                           const float* __restrict__ rs0, const float* __restrict__ bias) {
  const int row = blockIdx.x;
  const int t = threadIdx.x;
  if (t < KK / 4) {
    const float inv = 1.0f / (rs0[row] + P[(size_t)row * KP + KK]);
    float4 o = reinterpret_cast<const float4*>(out + (size_t)row * KK)[t];
    float4 p = reinterpret_cast<const float4*>(P + (size_t)row * KP)[t];
    float4 bv = reinterpret_cast<const float4*>(bias)[t];
    float4 r;
    r.x = (o.x + p.x) * inv + bv.x;
    r.y = (o.y + p.y) * inv + bv.y;
    r.z = (o.z + p.z) * inv + bv.z;
    r.w = (o.w + p.w) * inv + bv.w;
    reinterpret_cast<float4*>(out + (size_t)row * KK)[t] = r;
  }
}

// ---- workspace layout (bytes) ----
#define OFF_XB 0u                    // 8192*2048*2 = 33554432 (xb; reused as P after gemm1)
#define OFF_CB 33554432u             // 4096*2048*2 = 16777216
#define OFF_WB 50331648u             // 1024*4096*2 = 8388608
#define OFF_EB 58720256u             // 8192*4096*2 = 67108864
#define OFF_X2 125829120u            // 8192*4
#define OFF_C2 125861888u            // 4096*4
#define OFF_RS 125878272u            // 8192*4 (rs0: split-K=0 rowsum partial)
// P (split-K partial, 8192*1024*4 = 33554432) overlays OFF_XB — xb dead after gemm1.

extern "C" void kernel_launch(void* const* d_in, const int* in_sizes, int n_in,
                              void* d_out, int out_size, void* d_ws, size_t ws_size,
                              hipStream_t stream) {
  const float* x = (const float*)d_in[0];
  const float* cen = (const float*)d_in[1];
  const float* beta = (const float*)d_in[2];
  const float* W = (const float*)d_in[3];
  const float* bias = (const float*)d_in[4];
  float* out = (float*)d_out;
  char* ws = (char*)d_ws;

  u16* xb = (u16*)(ws + OFF_XB);
  u16* cb = (u16*)(ws + OFF_CB);
  u16* wb = (u16*)(ws + OFF_WB);
  u16* eb = (u16*)(ws + OFF_EB);
  float* x2 = (float*)(ws + OFF_X2);
  float* c2 = (float*)(ws + OFF_C2);
  float* rs0 = (float*)(ws + OFF_RS);
  float* P = (float*)(ws + OFF_XB);  // overlay on dead xb

  prep_all<<<BB + CC + KP, 256, 0, stream>>>(x, cen, W, xb, cb, wb, x2, c2);
  gemm1_rbf<<<dim3(CC / 128, BB / 256), 256, 0, stream>>>(xb, cb, x2, c2, beta, eb);
  gemm2_out<<<dim3(KP / 128, BB / 128, 2), 256, 0, stream>>>(eb, wb, out, P, rs0);
  reduce_out<<<BB, 256, 0, stream>>>(out, P, rs0, bias);
}